// Round 4
// baseline (249.949 us; speedup 1.0000x reference)
//
#include <hip/hip_runtime.h>
#include <stdint.h>

// RNN1: B=4096,T=256,E=27,H=64.
// a_{t+1} = tanh(a_t @ Waa^T + x_t @ Wax^T + ba), x_t = word[:,t-1,:] (0 at t=0)
// y[:,t,:] = a_{t+1} @ Wy^T + by
//
// Round 4 = round 3 with the x-prefetch addressing bug fixed (p[8*lg+k], was
// p[k] -- lanes lg>=1 read the wrong embedding slice).
//
// TRANSPOSED single-wave design. One 64-lane wave owns 16 batch rows and the
// full H=64 chain. State computed as state^T = Waa @ a^T:
//   A operand = weights (m = hidden-out, k = hidden-in via permutation sigma),
//   B operand = state   (n = batch = lane&15, slot (lg,j) holds s[sigma(lg,j)][b])
// D layout (n=lane&15=b, m=4*lg+reg) IS the sigma B-frag layout of the next
// step -> zero-cost feedback: no LDS, no barriers, no cross-lane ops in loop.
// sigma_f(lg,j) = (j<4 ? 4*lg+j : 12+4*lg+j) + 32*f ; weights pre-permuted.
// Numerics: split-bf16 state (hi+lo), 3 products (WH*sH, WH*sL, WL*sH) as in
// validated round 1 (absmax 0.0078). x and Wy single bf16.
// x prefetched 2 steps ahead (2 named reg sets, loop unrolled x2).

#define B_ 4096
#define T_ 256
#define E_ 27
#define H_ 64
#define WROW_ (H_ + E_)  // 91

typedef __bf16 bf16x8 __attribute__((ext_vector_type(8)));
typedef float f32x4 __attribute__((ext_vector_type(4)));
typedef unsigned int u32x4 __attribute__((ext_vector_type(4)));

static __device__ __forceinline__ unsigned pk2(float a, float b) {
  unsigned short ua = __builtin_bit_cast(unsigned short, (__bf16)a);
  unsigned short ub = __builtin_bit_cast(unsigned short, (__bf16)b);
  return (unsigned)ua | ((unsigned)ub << 16);
}
static __device__ __forceinline__ unsigned pkh(__bf16 a, __bf16 b) {
  unsigned short ua = __builtin_bit_cast(unsigned short, a);
  unsigned short ub = __builtin_bit_cast(unsigned short, b);
  return (unsigned)ua | ((unsigned)ub << 16);
}
static __device__ __forceinline__ float fast_tanh(float z) {
  // tanh(z) = 1 - 2/(exp(2z)+1); exp->inf / ->0 limits give +/-1 correctly
  float e = __expf(2.0f * z);
  float r = __builtin_amdgcn_rcpf(e + 1.0f);
  return __builtin_fmaf(-2.0f, r, 1.0f);
}
static __device__ __forceinline__ f32x4 MF(u32x4 a, u32x4 b, f32x4 c) {
  return __builtin_amdgcn_mfma_f32_16x16x32_bf16(
      __builtin_bit_cast(bf16x8, a), __builtin_bit_cast(bf16x8, b), c, 0, 0, 0);
}

__global__ __launch_bounds__(64, 1) void rnn_fused(
    const float* __restrict__ word, const float* __restrict__ Wa,
    const float* __restrict__ ba, const float* __restrict__ Wy,
    const float* __restrict__ by, float* __restrict__ out) {
  const int lane = threadIdx.x;
  const int p16 = lane & 15;  // batch row within group (n) / weight row (m)
  const int lg = lane >> 4;   // k-slot group
  const int rb = (int)blockIdx.x * 16;

  const float* const wrow = word + (size_t)(rb + p16) * (T_ * E_);
  float* const pout = out + (size_t)(rb + p16) * (T_ * E_);

  // ---- x prefetch sets: pf0 = word[-1] (zeros), pf1 <- word[0] ----
  float pf0[8], pf1[8];
#pragma unroll
  for (int k = 0; k < 8; ++k) pf0[k] = 0.f;
#pragma unroll
  for (int k = 0; k < 8; ++k) {
    const int e = 8 * lg + k;
    pf1[k] = (e < E_) ? wrow[8 * lg + k] : 0.f;
  }

  // ---- weight fragments, pre-permuted by sigma (registers, loop-invariant) --
  u32x4 WH[4][2], WL[4][2], WX[4], WY[2][2];
  float BA[4][4], BY[2][4];
#pragma unroll
  for (int mt = 0; mt < 4; ++mt) {
    const float* base = Wa + (16 * mt + p16) * WROW_;
#pragma unroll
    for (int f = 0; f < 2; ++f) {
#pragma unroll
      for (int v = 0; v < 4; ++v) {
        const int j = 2 * v;
        const int c = ((j < 4) ? (4 * lg + j) : (12 + 4 * lg + j)) + 32 * f;
        const float w0 = base[c], w1 = base[c + 1];
        const __bf16 h0 = (__bf16)w0, h1 = (__bf16)w1;
        WH[mt][f][v] = pkh(h0, h1);
        WL[mt][f][v] = pk2(w0 - (float)h0, w1 - (float)h1);
      }
    }
#pragma unroll
    for (int v = 0; v < 4; ++v) {  // Wax, natural k = e
      const int e0 = 8 * lg + 2 * v, e1 = e0 + 1;
      const float w0 = (e0 < E_) ? base[H_ + e0] : 0.f;
      const float w1 = (e1 < E_) ? base[H_ + e1] : 0.f;
      WX[mt][v] = pk2(w0, w1);
    }
  }
#pragma unroll
  for (int my = 0; my < 2; ++my) {  // Wy rows e = 16*my + p16, sigma k-cols
    const int e = 16 * my + p16;
    const bool valid = (e < E_);
    const float* rp = Wy + e * H_;
#pragma unroll
    for (int f = 0; f < 2; ++f) {
#pragma unroll
      for (int v = 0; v < 4; ++v) {
        const int j = 2 * v;
        const int c = ((j < 4) ? (4 * lg + j) : (12 + 4 * lg + j)) + 32 * f;
        const float w0 = valid ? rp[c] : 0.f;
        const float w1 = valid ? rp[c + 1] : 0.f;
        WY[my][f][v] = pk2(w0, w1);
      }
    }
  }
#pragma unroll
  for (int mt = 0; mt < 4; ++mt)
#pragma unroll
    for (int r = 0; r < 4; ++r) BA[mt][r] = ba[16 * mt + 4 * lg + r];
#pragma unroll
  for (int my = 0; my < 2; ++my)
#pragma unroll
    for (int r = 0; r < 4; ++r) {
      const int e = 16 * my + 4 * lg + r;
      BY[my][r] = (e < E_) ? by[e] : 0.f;
    }

  // ---- state frags (sigma layout), a0 = 0 ----
  u32x4 sH0 = {0u, 0u, 0u, 0u}, sH1 = sH0, sL0 = sH0, sL1 = sH0;

#define STEP(t, PF)                                                           \
  {                                                                           \
    u32x4 xf;                                                                 \
    xf[0] = pk2(PF[0], PF[1]);                                                \
    xf[1] = pk2(PF[2], PF[3]);                                                \
    xf[2] = pk2(PF[4], PF[5]);                                                \
    xf[3] = pk2(PF[6], PF[7]);                                                \
    if ((t) + 1 < T_) { /* prefetch word[t+1], used at step t+2 */            \
      const float* p = wrow + ((t) + 1) * E_;                                 \
      _Pragma("unroll") for (int k = 0; k < 8; ++k) {                         \
        const int e = 8 * lg + k;                                             \
        PF[k] = (e < E_) ? p[8 * lg + k] : 0.f; /* lane-offset load */        \
      }                                                                       \
    }                                                                         \
    f32x4 acc[4];                                                             \
    _Pragma("unroll") for (int mt = 0; mt < 4; ++mt) {                        \
      f32x4 a_ = {BA[mt][0], BA[mt][1], BA[mt][2], BA[mt][3]};                \
      a_ = MF(WH[mt][0], sH0, a_);                                            \
      a_ = MF(WH[mt][1], sH1, a_);                                            \
      a_ = MF(WL[mt][0], sH0, a_);                                            \
      a_ = MF(WX[mt], xf, a_);                                                \
      f32x4 b_ = {0.f, 0.f, 0.f, 0.f};                                        \
      b_ = MF(WH[mt][0], sL0, b_);                                            \
      b_ = MF(WH[mt][1], sL1, b_);                                            \
      b_ = MF(WL[mt][1], sH1, b_);                                            \
      acc[mt] = a_ + b_;                                                      \
    }                                                                         \
    unsigned hw[4][2], lw[4][2];                                              \
    _Pragma("unroll") for (int mt = 0; mt < 4; ++mt) {                        \
      const float t0 = fast_tanh(acc[mt][0]);                                 \
      const float t1 = fast_tanh(acc[mt][1]);                                 \
      const float t2 = fast_tanh(acc[mt][2]);                                 \
      const float t3 = fast_tanh(acc[mt][3]);                                 \
      const __bf16 h0 = (__bf16)t0, h1 = (__bf16)t1;                          \
      const __bf16 h2 = (__bf16)t2, h3 = (__bf16)t3;                          \
      hw[mt][0] = pkh(h0, h1);                                                \
      hw[mt][1] = pkh(h2, h3);                                                \
      lw[mt][0] = pk2(t0 - (float)h0, t1 - (float)h1);                        \
      lw[mt][1] = pk2(t2 - (float)h2, t3 - (float)h3);                        \
    }                                                                         \
    sH0[0] = hw[0][0]; sH0[1] = hw[0][1]; sH0[2] = hw[1][0]; sH0[3] = hw[1][1];\
    sH1[0] = hw[2][0]; sH1[1] = hw[2][1]; sH1[2] = hw[3][0]; sH1[3] = hw[3][1];\
    sL0[0] = lw[0][0]; sL0[1] = lw[0][1]; sL0[2] = lw[1][0]; sL0[3] = lw[1][1];\
    sL1[0] = lw[2][0]; sL1[1] = lw[2][1]; sL1[2] = lw[3][0]; sL1[3] = lw[3][1];\
    f32x4 y0 = {BY[0][0], BY[0][1], BY[0][2], BY[0][3]};                      \
    y0 = MF(WY[0][0], sH0, y0);                                               \
    y0 = MF(WY[0][1], sH1, y0);                                               \
    f32x4 y1 = {BY[1][0], BY[1][1], BY[1][2], BY[1][3]};                      \
    y1 = MF(WY[1][0], sH0, y1);                                               \
    y1 = MF(WY[1][1], sH1, y1);                                               \
    float* po = pout + (t)*E_;                                                \
    _Pragma("unroll") for (int r = 0; r < 4; ++r) po[4 * lg + r] = y0[r];     \
    _Pragma("unroll") for (int r = 0; r < 4; ++r) {                           \
      const int e = 16 + 4 * lg + r;                                          \
      if (e < E_) po[e] = y1[r];                                              \
    }                                                                         \
  }

  for (int t = 0; t < T_; t += 2) {
    STEP(t, pf0);
    STEP(t + 1, pf1);
  }
#undef STEP
}

extern "C" void kernel_launch(void* const* d_in, const int* in_sizes, int n_in,
                              void* d_out, int out_size, void* d_ws,
                              size_t ws_size, hipStream_t stream) {
  const float* word = (const float*)d_in[0];
  const float* Wa = (const float*)d_in[1];
  const float* ba = (const float*)d_in[2];
  const float* Wy = (const float*)d_in[3];
  const float* by = (const float*)d_in[4];
  float* out = (float*)d_out;
  rnn_fused<<<dim3(B_ / 16), dim3(64), 0, stream>>>(word, Wa, ba, Wy, by, out);
}